// Round 1
// baseline (339.521 us; speedup 1.0000x reference)
//
#include <hip/hip_runtime.h>
#include <hip/hip_bf16.h>

// UnifiedAttention: x->QKV gemm -> causal MHA (H=16,D=64) -> proj gemm
// B=2, N=2048, C=1024. bf16 MFMA (16x16x32) with fp32 accum throughout.

typedef __bf16 bf16x8 __attribute__((ext_vector_type(8)));
typedef __bf16 bf16x4 __attribute__((ext_vector_type(4)));
typedef float  f32x4  __attribute__((ext_vector_type(4)));

#define MFMA16(a, b, c) __builtin_amdgcn_mfma_f32_16x16x32_bf16((a), (b), (c), 0, 0, 0)

__device__ __forceinline__ void async_copy16(const __bf16* g, __bf16* l) {
    __builtin_amdgcn_global_load_lds(
        (const __attribute__((address_space(1))) void*)g,
        (__attribute__((address_space(3))) void*)l,
        16, 0, 0);
}

__device__ __forceinline__ float redmax16(float v) {
    v = fmaxf(v, __shfl_xor(v, 1));
    v = fmaxf(v, __shfl_xor(v, 2));
    v = fmaxf(v, __shfl_xor(v, 4));
    v = fmaxf(v, __shfl_xor(v, 8));
    return v;
}
__device__ __forceinline__ float redsum16(float v) {
    v += __shfl_xor(v, 1);
    v += __shfl_xor(v, 2);
    v += __shfl_xor(v, 4);
    v += __shfl_xor(v, 8);
    return v;
}

// ---------------- fp32 -> bf16 conversion (vectorized) ----------------
__global__ void f32_to_bf16_k(const float* __restrict__ in, __bf16* __restrict__ out, int n4) {
    int i = blockIdx.x * blockDim.x + threadIdx.x;
    if (i >= n4) return;
    float4 v = reinterpret_cast<const float4*>(in)[i];
    bf16x4 o;
    o[0] = (__bf16)v.x; o[1] = (__bf16)v.y; o[2] = (__bf16)v.z; o[3] = (__bf16)v.w;
    reinterpret_cast<bf16x4*>(out)[i] = o;
}

// ---------------- mask tile reduction: 64x64 tiles -> all-ones flag ----------------
__global__ void mask_reduce_k(const int* __restrict__ mask, int* __restrict__ mflag) {
    __shared__ int ok;
    const int t = threadIdx.x;
    if (t == 0) ok = 1;
    __syncthreads();
    const int jt = blockIdx.x & 31;
    const int it = (blockIdx.x >> 5) & 31;
    const int b  = blockIdx.x >> 10;
    bool all1 = true;
#pragma unroll
    for (int c = 0; c < 4; ++c) {
        const int row = c * 16 + (t >> 4);
        const int col = (t & 15) * 4;
        const int4 v = *reinterpret_cast<const int4*>(
            &mask[((size_t)(b * 2048 + it * 64 + row)) * 2048 + jt * 64 + col]);
        all1 = all1 && v.x && v.y && v.z && v.w;
    }
    if (!all1) ok = 0;
    __syncthreads();
    if (t == 0) mflag[(b * 32 + it) * 32 + jt] = ok;
}

// ---------------- GEMM C = A * Bm^T + bias  (A:[M,K], Bm:[N,K] row-major) ---------
// 128x128 tile, BK=64, 256 threads (4 waves 2x2, each wave 64x64 = 4x4 frags).
// EPI==0: fp32 out + bias. EPI==1: QKV scatter into q(scaled)/k/[vT] bf16.
template <int EPI>
__global__ __launch_bounds__(256) void gemm_bt_k(
    const __bf16* __restrict__ A, const __bf16* __restrict__ Bm,
    const float* __restrict__ bias, int M, int N, int K,
    float* __restrict__ outf, __bf16* __restrict__ qg,
    __bf16* __restrict__ kg, __bf16* __restrict__ vtg)
{
    __shared__ __align__(16) __bf16 As[128 * 64];
    __shared__ __align__(16) __bf16 Bs[128 * 64];
    const int t = threadIdx.x;
    const int nb = N >> 7;
    const int m0 = (blockIdx.x / nb) << 7;
    const int n0 = (blockIdx.x % nb) << 7;
    const int lane = t & 63, w = t >> 6;
    const int g = lane >> 4, li = lane & 15;
    const int wr = w >> 1, wc = w & 1;
    const __bf16* Ab = A + (size_t)m0 * K;
    const __bf16* Bb = Bm + (size_t)n0 * K;

    f32x4 acc[4][4] = {};

    for (int k0 = 0; k0 < K; k0 += 64) {
#pragma unroll
        for (int c = 0; c < 4; ++c) {
            const int e = (c * 256 + t) * 8;
            const int row = e >> 6;
            const int col = e & 63;
            async_copy16(Ab + (size_t)row * K + k0 + col, As + e);
            async_copy16(Bb + (size_t)row * K + k0 + col, Bs + e);
        }
        __syncthreads();  // drains vmcnt -> tiles resident
#pragma unroll
        for (int kk = 0; kk < 2; ++kk) {
            bf16x8 af[4], bf[4];
#pragma unroll
            for (int mi = 0; mi < 4; ++mi)
                af[mi] = *reinterpret_cast<const bf16x8*>(
                    &As[(wr * 64 + mi * 16 + li) * 64 + kk * 32 + g * 8]);
#pragma unroll
            for (int ni = 0; ni < 4; ++ni)
                bf[ni] = *reinterpret_cast<const bf16x8*>(
                    &Bs[(wc * 64 + ni * 16 + li) * 64 + kk * 32 + g * 8]);
#pragma unroll
            for (int mi = 0; mi < 4; ++mi)
#pragma unroll
                for (int ni = 0; ni < 4; ++ni)
                    acc[mi][ni] = MFMA16(af[mi], bf[ni], acc[mi][ni]);
        }
        __syncthreads();
    }

#pragma unroll
    for (int mi = 0; mi < 4; ++mi) {
#pragma unroll
        for (int ni = 0; ni < 4; ++ni) {
            const int n = n0 + wc * 64 + ni * 16 + li;
            const float bv = bias[n];
#pragma unroll
            for (int r = 0; r < 4; ++r) {
                const int m = m0 + wr * 64 + mi * 16 + g * 4 + r;
                const float v = acc[mi][ni][r] + bv;
                if constexpr (EPI == 0) {
                    outf[(size_t)m * N + n] = v;
                } else {
                    const int b = m >> 11, nn = m & 2047;
                    const int s = n >> 10, rem = n & 1023, h = rem >> 6, d = rem & 63;
                    const size_t head = (size_t)(b * 16 + h);
                    if (s == 0)      qg[(head * 2048 + nn) * 64 + d] = (__bf16)(v * 0.125f);
                    else if (s == 1) kg[(head * 2048 + nn) * 64 + d] = (__bf16)v;
                    else             vtg[(head * 64 + d) * 2048 + nn] = (__bf16)v;
                }
            }
        }
    }
}

// ---------------- flash attention, causal, 1 wave = 16 q-rows --------------------
// q:[BH,2048,64] (scale prefolded), k:[BH,2048,64], vT:[BH,64,2048] all bf16.
__global__ __launch_bounds__(256) void attn_k(
    const __bf16* __restrict__ qg, const __bf16* __restrict__ kg,
    const __bf16* __restrict__ vtg, const int* __restrict__ mflag,
    const int* __restrict__ mask, __bf16* __restrict__ ao)
{
    __shared__ __align__(16) __bf16 plds[4][16][72];  // per-wave P transpose buffer (+pad)
    const int t = threadIdx.x;
    const int w = t >> 6, lane = t & 63;
    const int g = lane >> 4, li = lane & 15;
    const int band = blockIdx.x & 31;
    const int h = (blockIdx.x >> 5) & 15;
    const int b = blockIdx.x >> 9;
    const int qrow0 = band * 64 + w * 16;
    const size_t hoff = (size_t)(b * 16 + h) * 2048 * 64;
    const __bf16* qh = qg + hoff;
    const __bf16* kh = kg + hoff;
    const __bf16* vh = vtg + hoff;

    bf16x8 qf[2];
#pragma unroll
    for (int kk = 0; kk < 2; ++kk)
        qf[kk] = *reinterpret_cast<const bf16x8*>(&qh[(size_t)(qrow0 + li) * 64 + kk * 32 + g * 8]);

    f32x4 o[4] = {};
    float mrun[4], lrun[4];
#pragma unroll
    for (int r = 0; r < 4; ++r) { mrun[r] = -1e30f; lrun[r] = 0.0f; }

    for (int kt = 0; kt <= band; ++kt) {
        // S = Q K^T  (16 q-rows x 64 keys)
        f32x4 s[4] = {};
#pragma unroll
        for (int nf = 0; nf < 4; ++nf) {
#pragma unroll
            for (int kk = 0; kk < 2; ++kk) {
                bf16x8 kf = *reinterpret_cast<const bf16x8*>(
                    &kh[(size_t)(kt * 64 + nf * 16 + li) * 64 + kk * 32 + g * 8]);
                s[nf] = MFMA16(qf[kk], kf, s[nf]);
            }
        }
        const bool pad = (mflag[(b * 32 + band) * 32 + kt] == 0);
        if (pad || kt == band) {
#pragma unroll
            for (int nf = 0; nf < 4; ++nf)
#pragma unroll
                for (int r = 0; r < 4; ++r) {
                    const int i = qrow0 + g * 4 + r;
                    const int j = kt * 64 + nf * 16 + li;
                    float v = s[nf][r];
                    if (j > i) v = -1e30f;  // causal
                    else if (pad && mask[((size_t)(b * 2048 + i)) * 2048 + j] == 0) v = -1e30f;
                    s[nf][r] = v;
                }
        }
        // online softmax (row i held by 16-lane group, 4 rows per lane-reg)
        float alpha[4], rs[4];
#pragma unroll
        for (int r = 0; r < 4; ++r) {
            float mt = fmaxf(fmaxf(s[0][r], s[1][r]), fmaxf(s[2][r], s[3][r]));
            mt = redmax16(mt);
            const float mn = fmaxf(mrun[r], mt);
            alpha[r] = __expf(mrun[r] - mn);
            mrun[r] = mn;
            rs[r] = 0.0f;
        }
#pragma unroll
        for (int nf = 0; nf < 4; ++nf)
#pragma unroll
            for (int r = 0; r < 4; ++r) {
                const float p = __expf(s[nf][r] - mrun[r]);
                s[nf][r] = p;
                rs[r] += p;
            }
#pragma unroll
        for (int r = 0; r < 4; ++r) {
            lrun[r] = lrun[r] * alpha[r] + redsum16(rs[r]);
            o[0][r] *= alpha[r];
            o[1][r] *= alpha[r];
            o[2][r] *= alpha[r];
            o[3][r] *= alpha[r];
        }
        // P -> LDS (C-layout positions), re-read as MFMA A-fragments
#pragma unroll
        for (int nf = 0; nf < 4; ++nf)
#pragma unroll
            for (int r = 0; r < 4; ++r)
                plds[w][g * 4 + r][nf * 16 + li] = (__bf16)s[nf][r];
        __syncthreads();
        bf16x8 pa[2];
#pragma unroll
        for (int kk = 0; kk < 2; ++kk)
            pa[kk] = *reinterpret_cast<const bf16x8*>(&plds[w][li][kk * 32 + g * 8]);
#pragma unroll
        for (int df = 0; df < 4; ++df) {
#pragma unroll
            for (int kk = 0; kk < 2; ++kk) {
                bf16x8 vf = *reinterpret_cast<const bf16x8*>(
                    &vh[(size_t)(df * 16 + li) * 2048 + kt * 64 + kk * 32 + g * 8]);
                o[df] = MFMA16(pa[kk], vf, o[df]);
            }
        }
        __syncthreads();
    }

    float inv[4];
#pragma unroll
    for (int r = 0; r < 4; ++r) inv[r] = 1.0f / lrun[r];
#pragma unroll
    for (int df = 0; df < 4; ++df)
#pragma unroll
        for (int r = 0; r < 4; ++r) {
            const int i = qrow0 + g * 4 + r;
            ao[((size_t)(b * 2048 + i)) * 1024 + h * 64 + df * 16 + li] =
                (__bf16)(o[df][r] * inv[r]);
        }
}

// ------------------------------- launch -----------------------------------------
extern "C" void kernel_launch(void* const* d_in, const int* in_sizes, int n_in,
                              void* d_out, int out_size, void* d_ws, size_t ws_size,
                              hipStream_t stream)
{
    const float* x      = (const float*)d_in[0];
    const int*   mask   = (const int*)d_in[1];
    const float* qkv_w  = (const float*)d_in[2];
    const float* qkv_b  = (const float*)d_in[3];
    const float* proj_w = (const float*)d_in[4];
    const float* proj_b = (const float*)d_in[5];
    float* out = (float*)d_out;

    char* ws = (char*)d_ws;
    __bf16* xb    = (__bf16*)(ws + 0);          // 4096x1024        8 MB
    __bf16* wqkv  = (__bf16*)(ws + 8388608);    // 3072x1024        6 MB
    __bf16* wproj = (__bf16*)(ws + 14680064);   // 1024x1024        2 MB
    __bf16* qg    = (__bf16*)(ws + 16777216);   // [32,2048,64]     8 MB
    __bf16* kg    = (__bf16*)(ws + 25165824);   // [32,2048,64]     8 MB
    __bf16* vtg   = (__bf16*)(ws + 33554432);   // [32,64,2048]     8 MB
    __bf16* ao    = (__bf16*)(ws + 41943040);   // 4096x1024        8 MB
    int*    mflag = (int*)(ws + 50331648);      // [2,32,32]        4 KB

    f32_to_bf16_k<<<1048576 / 256, 256, 0, stream>>>(x, xb, 1048576);
    f32_to_bf16_k<<<786432 / 256, 256, 0, stream>>>(qkv_w, wqkv, 786432);
    f32_to_bf16_k<<<262144 / 256, 256, 0, stream>>>(proj_w, wproj, 262144);
    mask_reduce_k<<<2 * 32 * 32, 256, 0, stream>>>(mask, mflag);
    gemm_bt_k<1><<<32 * 24, 256, 0, stream>>>(xb, wqkv, qkv_b, 4096, 3072, 1024,
                                              nullptr, qg, kg, vtg);
    attn_k<<<1024, 256, 0, stream>>>(qg, kg, vtg, mflag, mask, ao);
    gemm_bt_k<0><<<32 * 8, 256, 0, stream>>>(ao, wproj, proj_b, 4096, 1024, 1024,
                                             out, nullptr, nullptr, nullptr);
}

// Round 2
// 170.218 us; speedup vs baseline: 1.9946x; 1.9946x over previous
//
#include <hip/hip_runtime.h>
#include <hip/hip_bf16.h>

// UnifiedAttention: x->QKV gemm -> causal MHA (H=16,D=64) -> proj gemm
// B=2, N=2048, C=1024. bf16 MFMA with fp32 accum throughout.

typedef __bf16 bf16x8 __attribute__((ext_vector_type(8)));
typedef __bf16 bf16x4 __attribute__((ext_vector_type(4)));
typedef __bf16 bf16x2 __attribute__((ext_vector_type(2)));
typedef float  f32x4  __attribute__((ext_vector_type(4)));
typedef float  f32x16 __attribute__((ext_vector_type(16)));
typedef int    i32x4  __attribute__((ext_vector_type(4)));

#define MFMA16(a, b, c) __builtin_amdgcn_mfma_f32_16x16x32_bf16((a), (b), (c), 0, 0, 0)
#define MFMA32(a, b, c) __builtin_amdgcn_mfma_f32_32x32x16_bf16((a), (b), (c), 0, 0, 0)

__device__ __forceinline__ void async_copy16(const __bf16* g, __bf16* l) {
    __builtin_amdgcn_global_load_lds(
        (const __attribute__((address_space(1))) void*)g,
        (__attribute__((address_space(3))) void*)l,
        16, 0, 0);
}

__device__ __forceinline__ unsigned packbf(float a, float b) {
    union { bf16x2 v; unsigned u; } un;
    un.v[0] = (__bf16)a; un.v[1] = (__bf16)b;
    return un.u;
}

// ---------------- fp32 -> bf16 conversion (vectorized) ----------------
__global__ void f32_to_bf16_k(const float* __restrict__ in, __bf16* __restrict__ out, int n4) {
    int i = blockIdx.x * blockDim.x + threadIdx.x;
    if (i >= n4) return;
    float4 v = reinterpret_cast<const float4*>(in)[i];
    bf16x4 o;
    o[0] = (__bf16)v.x; o[1] = (__bf16)v.y; o[2] = (__bf16)v.z; o[3] = (__bf16)v.w;
    reinterpret_cast<bf16x4*>(out)[i] = o;
}

// ---------------- mask tile reduction: 64x64 tiles -> all-ones flag ----------------
__global__ void mask_reduce_k(const int* __restrict__ mask, int* __restrict__ mflag) {
    __shared__ int ok;
    const int t = threadIdx.x;
    if (t == 0) ok = 1;
    __syncthreads();
    const int jt = blockIdx.x & 31;
    const int it = (blockIdx.x >> 5) & 31;
    const int b  = blockIdx.x >> 10;
    bool all1 = true;
#pragma unroll
    for (int c = 0; c < 4; ++c) {
        const int row = c * 16 + (t >> 4);
        const int col = (t & 15) * 4;
        const int4 v = *reinterpret_cast<const int4*>(
            &mask[((size_t)(b * 2048 + it * 64 + row)) * 2048 + jt * 64 + col]);
        all1 = all1 && v.x && v.y && v.z && v.w;
    }
    if (!all1) ok = 0;
    __syncthreads();
    if (t == 0) mflag[(b * 32 + it) * 32 + jt] = ok;
}

// ---------------- GEMM C = A * Bm^T + bias  (A:[M,K], Bm:[N,K] row-major) ---------
template <int EPI>
__global__ __launch_bounds__(256) void gemm_bt_k(
    const __bf16* __restrict__ A, const __bf16* __restrict__ Bm,
    const float* __restrict__ bias, int M, int N, int K,
    float* __restrict__ outf, __bf16* __restrict__ qg,
    __bf16* __restrict__ kg, __bf16* __restrict__ vtg)
{
    __shared__ __align__(16) __bf16 As[128 * 64];
    __shared__ __align__(16) __bf16 Bs[128 * 64];
    const int t = threadIdx.x;
    const int nb = N >> 7;
    const int m0 = (blockIdx.x / nb) << 7;
    const int n0 = (blockIdx.x % nb) << 7;
    const int lane = t & 63, w = t >> 6;
    const int g = lane >> 4, li = lane & 15;
    const int wr = w >> 1, wc = w & 1;
    const __bf16* Ab = A + (size_t)m0 * K;
    const __bf16* Bb = Bm + (size_t)n0 * K;

    f32x4 acc[4][4] = {};

    for (int k0 = 0; k0 < K; k0 += 64) {
#pragma unroll
        for (int c = 0; c < 4; ++c) {
            const int e = (c * 256 + t) * 8;
            const int row = e >> 6;
            const int col = e & 63;
            async_copy16(Ab + (size_t)row * K + k0 + col, As + e);
            async_copy16(Bb + (size_t)row * K + k0 + col, Bs + e);
        }
        __syncthreads();
#pragma unroll
        for (int kk = 0; kk < 2; ++kk) {
            bf16x8 af[4], bf[4];
#pragma unroll
            for (int mi = 0; mi < 4; ++mi)
                af[mi] = *reinterpret_cast<const bf16x8*>(
                    &As[(wr * 64 + mi * 16 + li) * 64 + kk * 32 + g * 8]);
#pragma unroll
            for (int ni = 0; ni < 4; ++ni)
                bf[ni] = *reinterpret_cast<const bf16x8*>(
                    &Bs[(wc * 64 + ni * 16 + li) * 64 + kk * 32 + g * 8]);
#pragma unroll
            for (int mi = 0; mi < 4; ++mi)
#pragma unroll
                for (int ni = 0; ni < 4; ++ni)
                    acc[mi][ni] = MFMA16(af[mi], bf[ni], acc[mi][ni]);
        }
        __syncthreads();
    }

#pragma unroll
    for (int mi = 0; mi < 4; ++mi) {
#pragma unroll
        for (int ni = 0; ni < 4; ++ni) {
            const int n = n0 + wc * 64 + ni * 16 + li;
            const float bv = bias[n];
#pragma unroll
            for (int r = 0; r < 4; ++r) {
                const int m = m0 + wr * 64 + mi * 16 + g * 4 + r;
                const float v = acc[mi][ni][r] + bv;
                if constexpr (EPI == 0) {
                    outf[(size_t)m * N + n] = v;
                } else {
                    const int b = m >> 11, nn = m & 2047;
                    const int s = n >> 10, rem = n & 1023, hh = rem >> 6, d = rem & 63;
                    const size_t head = (size_t)(b * 16 + hh);
                    if (s == 0)      qg[(head * 2048 + nn) * 64 + d] = (__bf16)(v * 0.125f);
                    else if (s == 1) kg[(head * 2048 + nn) * 64 + d] = (__bf16)v;
                    else             vtg[(head * 64 + d) * 2048 + nn] = (__bf16)v;
                }
            }
        }
    }
}

// ---------------- flash attention, causal: 4 waves x 32 queries, KVBLK=64 ---------
// q:[BH,2048,64] (scale prefolded), k:[BH,2048,64], vT:[BH,64,2048] all bf16.
// Swapped QK^T (mfma(K,Q)) -> softmax lane-local per query. PV as mfma(vT,P).
// K/V double-buffered in LDS, XOR-swizzled (slot ^= row&7), staged via
// global_load_lds with pre-swizzled global source (both-sides swizzle).
__global__ __launch_bounds__(256) void attn_k(
    const __bf16* __restrict__ qg, const __bf16* __restrict__ kg,
    const __bf16* __restrict__ vtg, const int* __restrict__ mflag,
    const int* __restrict__ mask, __bf16* __restrict__ ao)
{
    __shared__ __align__(16) __bf16 Ks[2][4096];
    __shared__ __align__(16) __bf16 Vs[2][4096];
    const int t = threadIdx.x;
    const int w = t >> 6, lane = t & 63;
    const int h = lane >> 5, l31 = lane & 31;
    const int bb = blockIdx.x;
    const int band = 15 - (bb >> 5);      // heavy bands dispatch first
    const int hg = bb & 31;
    const int bI = hg >> 4, hI = hg & 15;
    const int q0w = (band << 7) + (w << 5);
    const int iq = q0w + l31;             // this lane's query row
    const size_t hoff = (size_t)hg * (2048 * 64);
    const __bf16* qh = qg + hoff;
    const __bf16* kh = kg + hoff;
    const __bf16* vh = vtg + hoff;

    // Q fragments: B-operand, lane holds Q[iq][dstep*16 + h*8 + j]
    bf16x8 qf[4];
#pragma unroll
    for (int ds2 = 0; ds2 < 4; ++ds2)
        qf[ds2] = *reinterpret_cast<const bf16x8*>(&qh[(size_t)iq * 64 + ds2 * 16 + h * 8]);

    f32x16 o0 = {}, o1 = {};
    float mrun = -1e30f, lrun = 0.0f;
    const int ktmax = 2 * band + 1;       // inclusive last tile staged by block
    const int diag = q0w >> 6;            // this wave's last compute tile
    const int rowt = q0w >> 6;            // mask row-tile (uniform in wave)

#define STAGE(bufv, ktv) do {                                                     \
    _Pragma("unroll")                                                             \
    for (int c = 0; c < 2; ++c) {                                                 \
        const int p = c * 4096 + t * 16;                                          \
        const int prow = p >> 7;                                                  \
        const int pslot = ((p >> 4) & 7) ^ (prow & 7);                            \
        async_copy16(kh + (size_t)((ktv) * 64 + prow) * 64 + pslot * 8,           \
                     (__bf16*)((char*)(&Ks[bufv][0]) + p));                       \
        async_copy16(vh + (size_t)prow * 2048 + (ktv) * 64 + pslot * 8,           \
                     (__bf16*)((char*)(&Vs[bufv][0]) + p));                       \
    }                                                                             \
} while (0)

    int cur = 0;
    STAGE(0, 0);
    for (int kt = 0; kt <= ktmax; ++kt) {
        __syncthreads();                  // buf[cur] staged; prior reads done
        if (kt < ktmax) STAGE(cur ^ 1, kt + 1);
        if (kt <= diag) {
            // ---- S^T = K Q^T : s[kb], lane holds S[key=crow(r,h)+32kb][query=l31]
            f32x16 s0 = {}, s1 = {};
            const int rsw = (l31 & 7);
#pragma unroll
            for (int ds2 = 0; ds2 < 4; ++ds2) {
                const int sl = ds2 * 2 + h;
                bf16x8 kf0 = *reinterpret_cast<const bf16x8*>(
                    (char*)(&Ks[cur][0]) + (l31 * 128 + ((sl ^ rsw) << 4)));
                bf16x8 kf1 = *reinterpret_cast<const bf16x8*>(
                    (char*)(&Ks[cur][0]) + ((32 + l31) * 128 + ((sl ^ rsw) << 4)));
                s0 = MFMA32(kf0, qf[ds2], s0);
                s1 = MFMA32(kf1, qf[ds2], s1);
            }
            // ---- causal / padding mask (diag tile only; pad path never taken here)
            const bool pflag = (mflag[(bI * 32 + rowt) * 32 + kt] == 0);
            if (pflag || kt == diag) {
                const int jb = kt * 64;
#pragma unroll
                for (int r = 0; r < 16; ++r) {
                    const int cr = (r & 3) + 8 * (r >> 2) + 4 * h;
                    const int j0 = jb + cr, j1 = jb + 32 + cr;
                    float v0 = s0[r], v1 = s1[r];
                    if (j0 > iq || (pflag && mask[((size_t)(bI * 2048 + iq)) * 2048 + j0] == 0)) v0 = -1e30f;
                    if (j1 > iq || (pflag && mask[((size_t)(bI * 2048 + iq)) * 2048 + j1] == 0)) v1 = -1e30f;
                    s0[r] = v0; s1[r] = v1;
                }
            }
            // ---- online softmax: lane-local (32 vals) + one cross-half reduce
            float mt = s0[0];
#pragma unroll
            for (int r = 1; r < 16; ++r) mt = fmaxf(mt, s0[r]);
#pragma unroll
            for (int r = 0; r < 16; ++r) mt = fmaxf(mt, s1[r]);
            mt = fmaxf(mt, __shfl_xor(mt, 32));
            const float mn = fmaxf(mrun, mt);
            const float alpha = __expf(mrun - mn);
            mrun = mn;
            float rs = 0.0f;
#pragma unroll
            for (int r = 0; r < 16; ++r) {
                const float p0 = __expf(s0[r] - mn); s0[r] = p0; rs += p0;
                const float p1 = __expf(s1[r] - mn); s1[r] = p1; rs += p1;
            }
            rs += __shfl_xor(rs, 32);
            lrun = lrun * alpha + rs;
#pragma unroll
            for (int r = 0; r < 16; ++r) { o0[r] *= alpha; o1[r] *= alpha; }
            // ---- P redistribution to PV B-operand (pack + cross-half exchange)
            bf16x8 pa[4];
#pragma unroll
            for (int ks = 0; ks < 4; ++ks) {
                const int c0 = (ks & 1) * 8;
                unsigned A0, A1, B0, B1;
                if (ks < 2) {
                    A0 = packbf(s0[c0 + 0], s0[c0 + 1]); A1 = packbf(s0[c0 + 2], s0[c0 + 3]);
                    B0 = packbf(s0[c0 + 4], s0[c0 + 5]); B1 = packbf(s0[c0 + 6], s0[c0 + 7]);
                } else {
                    A0 = packbf(s1[c0 + 0], s1[c0 + 1]); A1 = packbf(s1[c0 + 2], s1[c0 + 3]);
                    B0 = packbf(s1[c0 + 4], s1[c0 + 5]); B1 = packbf(s1[c0 + 6], s1[c0 + 7]);
                }
                const unsigned Z0 = h ? A0 : B0;       // send what partner needs
                const unsigned Z1 = h ? A1 : B1;
                const unsigned X0 = (unsigned)__shfl_xor((int)Z0, 32);
                const unsigned X1 = (unsigned)__shfl_xor((int)Z1, 32);
                i32x4 wv;
                wv[0] = (int)(h ? X0 : A0);
                wv[1] = (int)(h ? X1 : A1);
                wv[2] = (int)(h ? B0 : X0);
                wv[3] = (int)(h ? B1 : X1);
                pa[ks] = __builtin_bit_cast(bf16x8, wv);
            }
            // ---- O += V^T P : A = vT rows (d), B = pa
#pragma unroll
            for (int ks = 0; ks < 4; ++ks) {
                const int sl = ks * 2 + h;
                bf16x8 vf0 = *reinterpret_cast<const bf16x8*>(
                    (char*)(&Vs[cur][0]) + (l31 * 128 + ((sl ^ rsw) << 4)));
                bf16x8 vf1 = *reinterpret_cast<const bf16x8*>(
                    (char*)(&Vs[cur][0]) + ((32 + l31) * 128 + ((sl ^ rsw) << 4)));
                o0 = MFMA32(vf0, pa[ks], o0);
                o1 = MFMA32(vf1, pa[ks], o1);
            }
        }
        cur ^= 1;
    }
#undef STAGE

    // ---- epilogue: normalize, write ao[b][iq][hI*64 + d], d = 32db+8rq+4h+c
    const float inv = 1.0f / lrun;
    __bf16* aor = ao + ((size_t)(bI * 2048 + iq)) * 1024 + hI * 64 + h * 4;
#pragma unroll
    for (int rq = 0; rq < 4; ++rq) {
        bf16x4 st0, st1;
#pragma unroll
        for (int c2 = 0; c2 < 4; ++c2) {
            st0[c2] = (__bf16)(o0[rq * 4 + c2] * inv);
            st1[c2] = (__bf16)(o1[rq * 4 + c2] * inv);
        }
        *reinterpret_cast<bf16x4*>(&aor[rq * 8])      = st0;
        *reinterpret_cast<bf16x4*>(&aor[32 + rq * 8]) = st1;
    }
}

// ------------------------------- launch -----------------------------------------
extern "C" void kernel_launch(void* const* d_in, const int* in_sizes, int n_in,
                              void* d_out, int out_size, void* d_ws, size_t ws_size,
                              hipStream_t stream)
{
    const float* x      = (const float*)d_in[0];
    const int*   mask   = (const int*)d_in[1];
    const float* qkv_w  = (const float*)d_in[2];
    const float* qkv_b  = (const float*)d_in[3];
    const float* proj_w = (const float*)d_in[4];
    const float* proj_b = (const float*)d_in[5];
    float* out = (float*)d_out;

    char* ws = (char*)d_ws;
    __bf16* xb    = (__bf16*)(ws + 0);          // 4096x1024        8 MB
    __bf16* wqkv  = (__bf16*)(ws + 8388608);    // 3072x1024        6 MB
    __bf16* wproj = (__bf16*)(ws + 14680064);   // 1024x1024        2 MB
    __bf16* qg    = (__bf16*)(ws + 16777216);   // [32,2048,64]     8 MB
    __bf16* kg    = (__bf16*)(ws + 25165824);   // [32,2048,64]     8 MB
    __bf16* vtg   = (__bf16*)(ws + 33554432);   // [32,64,2048]     8 MB
    __bf16* ao    = (__bf16*)(ws + 41943040);   // 4096x1024        8 MB
    int*    mflag = (int*)(ws + 50331648);      // [2,32,32]        4 KB

    f32_to_bf16_k<<<1048576 / 256, 256, 0, stream>>>(x, xb, 1048576);
    f32_to_bf16_k<<<786432 / 256, 256, 0, stream>>>(qkv_w, wqkv, 786432);
    f32_to_bf16_k<<<262144 / 256, 256, 0, stream>>>(proj_w, wproj, 262144);
    mask_reduce_k<<<2 * 32 * 32, 256, 0, stream>>>(mask, mflag);
    gemm_bt_k<1><<<32 * 24, 256, 0, stream>>>(xb, wqkv, qkv_b, 4096, 3072, 1024,
                                              nullptr, qg, kg, vtg);
    attn_k<<<512, 256, 0, stream>>>(qg, kg, vtg, mflag, mask, ao);
    gemm_bt_k<0><<<32 * 8, 256, 0, stream>>>(ao, wproj, proj_b, 4096, 1024, 1024,
                                             out, nullptr, nullptr, nullptr);
}

// Round 3
// 146.133 us; speedup vs baseline: 2.3234x; 1.1648x over previous
//
#include <hip/hip_runtime.h>
#include <hip/hip_bf16.h>

// UnifiedAttention: x->QKV gemm -> causal MHA (H=16,D=64) -> proj gemm
// B=2, N=2048, C=1024. bf16 MFMA with fp32 accum throughout.

typedef __bf16 bf16x8 __attribute__((ext_vector_type(8)));
typedef __bf16 bf16x4 __attribute__((ext_vector_type(4)));
typedef __bf16 bf16x2 __attribute__((ext_vector_type(2)));
typedef float  f32x4  __attribute__((ext_vector_type(4)));
typedef float  f32x16 __attribute__((ext_vector_type(16)));
typedef int    i32x4  __attribute__((ext_vector_type(4)));

#define MFMA16(a, b, c) __builtin_amdgcn_mfma_f32_16x16x32_bf16((a), (b), (c), 0, 0, 0)
#define MFMA32(a, b, c) __builtin_amdgcn_mfma_f32_32x32x16_bf16((a), (b), (c), 0, 0, 0)

__device__ __forceinline__ void async_copy16(const __bf16* g, __bf16* l) {
    __builtin_amdgcn_global_load_lds(
        (const __attribute__((address_space(1))) void*)g,
        (__attribute__((address_space(3))) void*)l,
        16, 0, 0);
}

__device__ __forceinline__ unsigned packbf(float a, float b) {
    union { bf16x2 v; unsigned u; } un;
    un.v[0] = (__bf16)a; un.v[1] = (__bf16)b;
    return un.u;
}

// ---------------- fp32 -> bf16 conversion (vectorized) ----------------
__global__ void f32_to_bf16_k(const float* __restrict__ in, __bf16* __restrict__ out, int n4) {
    int i = blockIdx.x * blockDim.x + threadIdx.x;
    if (i >= n4) return;
    float4 v = reinterpret_cast<const float4*>(in)[i];
    bf16x4 o;
    o[0] = (__bf16)v.x; o[1] = (__bf16)v.y; o[2] = (__bf16)v.z; o[3] = (__bf16)v.w;
    reinterpret_cast<bf16x4*>(out)[i] = o;
}

// ---------------- mask tile reduction: 64x64 tiles -> all-ones flag ----------------
__global__ void mask_reduce_k(const int* __restrict__ mask, int* __restrict__ mflag) {
    __shared__ int ok;
    const int t = threadIdx.x;
    if (t == 0) ok = 1;
    __syncthreads();
    const int jt = blockIdx.x & 31;
    const int it = (blockIdx.x >> 5) & 31;
    const int b  = blockIdx.x >> 10;
    bool all1 = true;
#pragma unroll
    for (int c = 0; c < 4; ++c) {
        const int row = c * 16 + (t >> 4);
        const int col = (t & 15) * 4;
        const int4 v = *reinterpret_cast<const int4*>(
            &mask[((size_t)(b * 2048 + it * 64 + row)) * 2048 + jt * 64 + col]);
        all1 = all1 && v.x && v.y && v.z && v.w;
    }
    if (!all1) ok = 0;
    __syncthreads();
    if (t == 0) mflag[(b * 32 + it) * 32 + jt] = ok;
}

// ============ 8-phase 256x256 QKV GEMM (T1+T2+T3+T4+T5), K=1024 =================
// C = A * Bm^T + bias, scatter epilogue into q(scaled)/k/vT.
// 512 threads = 8 waves (2M x 4N), per-wave C = 128x64, BK=64, dbuf LDS 128KB.
// Counted vmcnt(2): stage half-tiles of K-tile T at phases {(T-2)P4,(T-1)P1..P3};
// deadline (T-1)P4's vmcnt(2)+barrier => all of tile T landed, 1 half in flight.
#define BAR() asm volatile("s_barrier" ::: "memory")
#define VM2() asm volatile("s_waitcnt vmcnt(2)" ::: "memory")

__global__ __launch_bounds__(512, 2) void gemm_qkv8_k(
    const __bf16* __restrict__ A, const __bf16* __restrict__ Bm,
    const float* __restrict__ bias,
    __bf16* __restrict__ qg, __bf16* __restrict__ kg, __bf16* __restrict__ vtg)
{
    __shared__ __align__(16) __bf16 As[2][16384];   // [buf][256 rows x 64]
    __shared__ __align__(16) __bf16 Bs[2][16384];

    const int t = threadIdx.x;
    const int lane = t & 63;
    const int w = t >> 6;
    const int wr = w >> 2, wc = w & 3;
    const int li = lane & 15, g = lane >> 4;

    // XCD-aware bijective swizzle (grid=192, 192%8==0, 24 blocks per XCD)
    const int bid = (blockIdx.x & 7) * 24 + (blockIdx.x >> 3);
    const int m0 = (bid / 12) << 8;     // N tiles = 3072/256 = 12
    const int n0 = (bid % 12) << 8;

    // staging: thread t covers LDS bytes [t*16, t*16+16) of each 8KB issue.
    // LDS row = hh*128 + issue*64 + (t>>3); slot(16B) = t&7.
    // swizzle: LDS slot s holds global col-slot s ^ (row&7)  (row&7 == (t>>3)&7)
    const int srow = t >> 3;
    const int scol = ((t & 7) ^ (srow & 7)) << 3;
    const __bf16* pA = A  + (size_t)(m0 + srow) * 1024 + scol;
    const __bf16* pB = Bm + (size_t)(n0 + srow) * 1024 + scol;
    __bf16* dA = &As[0][0] + t * 8;
    __bf16* dB = &Bs[0][0] + t * 8;

#define STAGE_A(BB, T, HH) do {                                                   \
    const size_t ro_ = (size_t)((HH) * 128) * 1024 + (size_t)(T) * 64;            \
    async_copy16(pA + ro_,         dA + (BB) * 16384 + (HH) * 8192);              \
    async_copy16(pA + ro_ + 65536, dA + (BB) * 16384 + (HH) * 8192 + 4096);       \
  } while (0)
#define STAGE_B(BB, T, HH) do {                                                   \
    const size_t ro_ = (size_t)((HH) * 128) * 1024 + (size_t)(T) * 64;            \
    async_copy16(pB + ro_,         dB + (BB) * 16384 + (HH) * 8192);              \
    async_copy16(pB + ro_ + 65536, dB + (BB) * 16384 + (HH) * 8192 + 4096);       \
  } while (0)

    // ds_read: frag row = base + li; phys slot = (ks*4+g) ^ (li&7)
    const int aoff0 = ((0 + g) ^ (li & 7)) << 3;
    const int aoff1 = ((4 + g) ^ (li & 7)) << 3;
    const int abase = (wr * 128 + li) * 64;
    const int bbase = (wc * 64 + li) * 64;

    f32x4 acc[8][4] = {};
    bf16x8 a[4][2], b[2][2][2];

#define READ_A(BB, MH) do { _Pragma("unroll")                                     \
    for (int mi2 = 0; mi2 < 4; ++mi2) {                                           \
      const __bf16* p_ = &As[BB][abase + ((MH) * 4 + mi2) * 1024];                \
      a[mi2][0] = *reinterpret_cast<const bf16x8*>(p_ + aoff0);                   \
      a[mi2][1] = *reinterpret_cast<const bf16x8*>(p_ + aoff1); } } while (0)
#define READ_B(BB, NH) do { _Pragma("unroll")                                     \
    for (int ni2 = 0; ni2 < 2; ++ni2) {                                           \
      const __bf16* p_ = &Bs[BB][bbase + ((NH) * 2 + ni2) * 1024];                \
      b[NH][ni2][0] = *reinterpret_cast<const bf16x8*>(p_ + aoff0);               \
      b[NH][ni2][1] = *reinterpret_cast<const bf16x8*>(p_ + aoff1); } } while (0)
#define MFMA_QUAD(MH, NH) do {                                                    \
    __builtin_amdgcn_s_setprio(1);                                                \
    _Pragma("unroll") for (int mi2 = 0; mi2 < 4; ++mi2)                           \
    _Pragma("unroll") for (int ni2 = 0; ni2 < 2; ++ni2) {                         \
      f32x4 c_ = acc[(MH) * 4 + mi2][(NH) * 2 + ni2];                             \
      c_ = MFMA16(a[mi2][0], b[NH][ni2][0], c_);                                  \
      c_ = MFMA16(a[mi2][1], b[NH][ni2][1], c_);                                  \
      acc[(MH) * 4 + mi2][(NH) * 2 + ni2] = c_; }                                 \
    __builtin_amdgcn_s_setprio(0); } while (0)

#define KTILE(BB, T) do {                                                         \
    const int Tn_  = ((T) + 1 < 16) ? (T) + 1 : 15;                               \
    const int Tn2_ = ((T) + 2 < 16) ? (T) + 2 : 15;                               \
    STAGE_A((BB) ^ 1, Tn_, 1);                                                    \
    READ_A(BB, 0); READ_B(BB, 0);                                                 \
    BAR(); MFMA_QUAD(0, 0); BAR();                                                \
    STAGE_B((BB) ^ 1, Tn_, 0);                                                    \
    READ_B(BB, 1);                                                                \
    BAR(); MFMA_QUAD(0, 1); BAR();                                                \
    STAGE_B((BB) ^ 1, Tn_, 1);                                                    \
    READ_A(BB, 1);                                                                \
    BAR(); MFMA_QUAD(1, 0); BAR();                                                \
    STAGE_A((BB), Tn2_, 0);                                                       \
    VM2(); BAR(); MFMA_QUAD(1, 1); BAR();                                         \
  } while (0)

    // prologue: tile0 all halves + tile1 Ah0; vmcnt(2) => tile0 landed
    STAGE_A(0, 0, 0); STAGE_A(0, 0, 1);
    STAGE_B(0, 0, 0); STAGE_B(0, 0, 1);
    STAGE_A(1, 1, 0);
    VM2(); BAR();

#pragma unroll 1
    for (int jj = 0; jj < 8; ++jj) {
        KTILE(0, 2 * jj);
        KTILE(1, 2 * jj + 1);
    }

    // ---- epilogue: scatter into q (scaled) / k / vT; wave n-range = one (s,head)
    const int nbase = n0 + wc * 64;
    const int s = nbase >> 10;
    const int headg = (m0 >> 11) * 16 + ((nbase & 1023) >> 6);
    const int mrow = (m0 & 2047) + wr * 128 + g * 4;   // + mi*16 + r
    float bv[4];
#pragma unroll
    for (int ni = 0; ni < 4; ++ni) bv[ni] = bias[nbase + ni * 16 + li];

    if (s == 2) {
#pragma unroll
        for (int mi = 0; mi < 8; ++mi) {
#pragma unroll
            for (int ni = 0; ni < 4; ++ni) {
                bf16x4 st;
#pragma unroll
                for (int r = 0; r < 4; ++r) st[r] = (__bf16)(acc[mi][ni][r] + bv[ni]);
                *reinterpret_cast<bf16x4*>(
                    &vtg[((size_t)(headg * 64) + ni * 16 + li) * 2048 + mrow + mi * 16]) = st;
            }
        }
    } else {
        __bf16* og = (s == 0) ? qg : kg;
        const float sc = (s == 0) ? 0.125f : 1.0f;
#pragma unroll
        for (int mi = 0; mi < 8; ++mi) {
#pragma unroll
            for (int r = 0; r < 4; ++r) {
                __bf16* rp = og + ((size_t)headg * 2048 + mrow + mi * 16 + r) * 64;
#pragma unroll
                for (int ni = 0; ni < 4; ++ni)
                    rp[ni * 16 + li] = (__bf16)((acc[mi][ni][r] + bv[ni]) * sc);
            }
        }
    }
#undef KTILE
#undef MFMA_QUAD
#undef READ_A
#undef READ_B
#undef STAGE_A
#undef STAGE_B
}

// ---------------- 2-phase 128x128 GEMM (proj): C = A*Bm^T + bias, fp32 out -------
__global__ __launch_bounds__(256) void gemm_proj_k(
    const __bf16* __restrict__ A, const __bf16* __restrict__ Bm,
    const float* __restrict__ bias, int M, int N, int K,
    float* __restrict__ outf)
{
    __shared__ __align__(16) __bf16 Asل[1]; // placeholder avoided
    (void)Asل;
}

// (real proj kernel below -- kept identical to the verified round-2 template)
template <int EPI>
__global__ __launch_bounds__(256) void gemm_bt_k(
    const __bf16* __restrict__ A, const __bf16* __restrict__ Bm,
    const float* __restrict__ bias, int M, int N, int K,
    float* __restrict__ outf)
{
    __shared__ __align__(16) __bf16 As[128 * 64];
    __shared__ __align__(16) __bf16 Bs[128 * 64];
    const int t = threadIdx.x;
    const int nb = N >> 7;
    const int m0 = (blockIdx.x / nb) << 7;
    const int n0 = (blockIdx.x % nb) << 7;
    const int lane = t & 63, w = t >> 6;
    const int g = lane >> 4, li = lane & 15;
    const int wr = w >> 1, wc = w & 1;
    const __bf16* Ab = A + (size_t)m0 * K;
    const __bf16* Bb = Bm + (size_t)n0 * K;

    f32x4 acc[4][4] = {};

    for (int k0 = 0; k0 < K; k0 += 64) {
#pragma unroll
        for (int c = 0; c < 4; ++c) {
            const int e = (c * 256 + t) * 8;
            const int row = e >> 6;
            const int col = e & 63;
            async_copy16(Ab + (size_t)row * K + k0 + col, As + e);
            async_copy16(Bb + (size_t)row * K + k0 + col, Bs + e);
        }
        __syncthreads();
#pragma unroll
        for (int kk = 0; kk < 2; ++kk) {
            bf16x8 af[4], bf[4];
#pragma unroll
            for (int mi = 0; mi < 4; ++mi)
                af[mi] = *reinterpret_cast<const bf16x8*>(
                    &As[(wr * 64 + mi * 16 + li) * 64 + kk * 32 + g * 8]);
#pragma unroll
            for (int ni = 0; ni < 4; ++ni)
                bf[ni] = *reinterpret_cast<const bf16x8*>(
                    &Bs[(wc * 64 + ni * 16 + li) * 64 + kk * 32 + g * 8]);
#pragma unroll
            for (int mi = 0; mi < 4; ++mi)
#pragma unroll
                for (int ni = 0; ni < 4; ++ni)
                    acc[mi][ni] = MFMA16(af[mi], bf[ni], acc[mi][ni]);
        }
        __syncthreads();
    }

#pragma unroll
    for (int mi = 0; mi < 4; ++mi) {
#pragma unroll
        for (int ni = 0; ni < 4; ++ni) {
            const int n = n0 + wc * 64 + ni * 16 + li;
            const float bv = bias[n];
#pragma unroll
            for (int r = 0; r < 4; ++r) {
                const int m = m0 + wr * 64 + mi * 16 + g * 4 + r;
                outf[(size_t)m * N + n] = acc[mi][ni][r] + bv;
            }
        }
    }
}

// ---------------- flash attention, causal: 4 waves x 32 queries, KVBLK=64 ---------
__global__ __launch_bounds__(256) void attn_k(
    const __bf16* __restrict__ qg, const __bf16* __restrict__ kg,
    const __bf16* __restrict__ vtg, const int* __restrict__ mflag,
    const int* __restrict__ mask, __bf16* __restrict__ ao)
{
    __shared__ __align__(16) __bf16 Ks[2][4096];
    __shared__ __align__(16) __bf16 Vs[2][4096];
    const int t = threadIdx.x;
    const int w = t >> 6, lane = t & 63;
    const int h = lane >> 5, l31 = lane & 31;
    const int bb = blockIdx.x;
    const int band = 15 - (bb >> 5);      // heavy bands dispatch first
    const int hg = bb & 31;
    const int bI = hg >> 4, hI = hg & 15;
    const int q0w = (band << 7) + (w << 5);
    const int iq = q0w + l31;
    const size_t hoff = (size_t)hg * (2048 * 64);
    const __bf16* qh = qg + hoff;
    const __bf16* kh = kg + hoff;
    const __bf16* vh = vtg + hoff;

    bf16x8 qf[4];
#pragma unroll
    for (int ds2 = 0; ds2 < 4; ++ds2)
        qf[ds2] = *reinterpret_cast<const bf16x8*>(&qh[(size_t)iq * 64 + ds2 * 16 + h * 8]);

    f32x16 o0 = {}, o1 = {};
    float mrun = -1e30f, lrun = 0.0f;
    const int ktmax = 2 * band + 1;
    const int diag = q0w >> 6;
    const int rowt = q0w >> 6;

#define STAGE(bufv, ktv) do {                                                     \
    _Pragma("unroll")                                                             \
    for (int c = 0; c < 2; ++c) {                                                 \
        const int p = c * 4096 + t * 16;                                          \
        const int prow = p >> 7;                                                  \
        const int pslot = ((p >> 4) & 7) ^ (prow & 7);                            \
        async_copy16(kh + (size_t)((ktv) * 64 + prow) * 64 + pslot * 8,           \
                     (__bf16*)((char*)(&Ks[bufv][0]) + p));                       \
        async_copy16(vh + (size_t)prow * 2048 + (ktv) * 64 + pslot * 8,           \
                     (__bf16*)((char*)(&Vs[bufv][0]) + p));                       \
    }                                                                             \
} while (0)

    int cur = 0;
    STAGE(0, 0);
    for (int kt = 0; kt <= ktmax; ++kt) {
        __syncthreads();
        if (kt < ktmax) STAGE(cur ^ 1, kt + 1);
        if (kt <= diag) {
            f32x16 s0 = {}, s1 = {};
            const int rsw = (l31 & 7);
#pragma unroll
            for (int ds2 = 0; ds2 < 4; ++ds2) {
                const int sl = ds2 * 2 + h;
                bf16x8 kf0 = *reinterpret_cast<const bf16x8*>(
                    (char*)(&Ks[cur][0]) + (l31 * 128 + ((sl ^ rsw) << 4)));
                bf16x8 kf1 = *reinterpret_cast<const bf16x8*>(
                    (char*)(&Ks[cur][0]) + ((32 + l31) * 128 + ((sl ^ rsw) << 4)));
                s0 = MFMA32(kf0, qf[ds2], s0);
                s1 = MFMA32(kf1, qf[ds2], s1);
            }
            const bool pflag = (mflag[(bI * 32 + rowt) * 32 + kt] == 0);
            if (pflag || kt == diag) {
                const int jb = kt * 64;
#pragma unroll
                for (int r = 0; r < 16; ++r) {
                    const int cr = (r & 3) + 8 * (r >> 2) + 4 * h;
                    const int j0 = jb + cr, j1 = jb + 32 + cr;
                    float v0 = s0[r], v1 = s1[r];
                    if (j0 > iq || (pflag && mask[((size_t)(bI * 2048 + iq)) * 2048 + j0] == 0)) v0 = -1e30f;
                    if (j1 > iq || (pflag && mask[((size_t)(bI * 2048 + iq)) * 2048 + j1] == 0)) v1 = -1e30f;
                    s0[r] = v0; s1[r] = v1;
                }
            }
            float mt = s0[0];
#pragma unroll
            for (int r = 1; r < 16; ++r) mt = fmaxf(mt, s0[r]);
#pragma unroll
            for (int r = 0; r < 16; ++r) mt = fmaxf(mt, s1[r]);
            mt = fmaxf(mt, __shfl_xor(mt, 32));
            const float mn = fmaxf(mrun, mt);
            const float alpha = __expf(mrun - mn);
            mrun = mn;
            float rs = 0.0f;
#pragma unroll
            for (int r = 0; r < 16; ++r) {
                const float p0 = __expf(s0[r] - mn); s0[r] = p0; rs += p0;
                const float p1 = __expf(s1[r] - mn); s1[r] = p1; rs += p1;
            }
            rs += __shfl_xor(rs, 32);
            lrun = lrun * alpha + rs;
#pragma unroll
            for (int r = 0; r < 16; ++r) { o0[r] *= alpha; o1[r] *= alpha; }
            bf16x8 pa[4];
#pragma unroll
            for (int ks = 0; ks < 4; ++ks) {
                const int c0 = (ks & 1) * 8;
                unsigned A0, A1, B0, B1;
                if (ks < 2) {
                    A0 = packbf(s0[c0 + 0], s0[c0 + 1]); A1 = packbf(s0[c0 + 2], s0[c0 + 3]);
                    B0 = packbf(s0[c0 + 4], s0[c0 + 5]); B1 = packbf(s0[c0 + 6], s0[c0 + 7]);
                } else {
                    A0 = packbf(s1[c0 + 0], s1[c0 + 1]); A1 = packbf(s1[c0 + 2], s1[c0 + 3]);
                    B0 = packbf(s1[c0 + 4], s1[c0 + 5]); B1 = packbf(s1[c0 + 6], s1[c0 + 7]);
                }
                const unsigned Z0 = h ? A0 : B0;
                const unsigned Z1 = h ? A1 : B1;
                const unsigned X0 = (unsigned)__shfl_xor((int)Z0, 32);
                const unsigned X1 = (unsigned)__shfl_xor((int)Z1, 32);
                i32x4 wv;
                wv[0] = (int)(h ? X0 : A0);
                wv[1] = (int)(h ? X1 : A1);
                wv[2] = (int)(h ? B0 : X0);
                wv[3] = (int)(h ? B1 : X1);
                pa[ks] = __builtin_bit_cast(bf16x8, wv);
            }
#pragma unroll
            for (int ks = 0; ks < 4; ++ks) {
                const int sl = ks * 2 + h;
                bf16x8 vf0 = *reinterpret_cast<const bf16x8*>(
                    (char*)(&Vs[cur][0]) + (l31 * 128 + ((sl ^ rsw) << 4)));
                bf16x8 vf1 = *reinterpret_cast<const bf16x8*>(
                    (char*)(&Vs[cur][0]) + ((32 + l31) * 128 + ((sl ^ rsw) << 4)));
                o0 = MFMA32(vf0, pa[ks], o0);
                o1 = MFMA32(vf1, pa[ks], o1);
            }
        }
        cur ^= 1;
    }
#undef STAGE

    const float inv = 1.0f / lrun;
    __bf16* aor = ao + ((size_t)(bI * 2048 + iq)) * 1024 + hI * 64 + h * 4;
#pragma unroll
    for (int rq = 0; rq < 4; ++rq) {
        bf16x4 st0, st1;
#pragma unroll
        for (int c2 = 0; c2 < 4; ++c2) {
            st0[c2] = (__bf16)(o0[rq * 4 + c2] * inv);
            st1[c2] = (__bf16)(o1[rq * 4 + c2] * inv);
        }
        *reinterpret_cast<bf16x4*>(&aor[rq * 8])      = st0;
        *reinterpret_cast<bf16x4*>(&aor[32 + rq * 8]) = st1;
    }
}

// ------------------------------- launch -----------------------------------------
extern "C" void kernel_launch(void* const* d_in, const int* in_sizes, int n_in,
                              void* d_out, int out_size, void* d_ws, size_t ws_size,
                              hipStream_t stream)
{
    const float* x      = (const float*)d_in[0];
    const int*   mask   = (const int*)d_in[1];
    const float* qkv_w  = (const float*)d_in[2];
    const float* qkv_b  = (const float*)d_in[3];
    const float* proj_w = (const float*)d_in[4];
    const float* proj_b = (const float*)d_in[5];
    float* out = (float*)d_out;

    char* ws = (char*)d_ws;
    __bf16* xb    = (__bf16*)(ws + 0);          // 4096x1024        8 MB
    __bf16* wqkv  = (__bf16*)(ws + 8388608);    // 3072x1024        6 MB
    __bf16* wproj = (__bf16*)(ws + 14680064);   // 1024x1024        2 MB
    __bf16* qg    = (__bf16*)(ws + 16777216);   // [32,2048,64]     8 MB
    __bf16* kg    = (__bf16*)(ws + 25165824);   // [32,2048,64]     8 MB
    __bf16* vtg   = (__bf16*)(ws + 33554432);   // [32,64,2048]     8 MB
    __bf16* ao    = (__bf16*)(ws + 41943040);   // 4096x1024        8 MB
    int*    mflag = (int*)(ws + 50331648);      // [2,32,32]        4 KB

    f32_to_bf16_k<<<1048576 / 256, 256, 0, stream>>>(x, xb, 1048576);
    f32_to_bf16_k<<<786432 / 256, 256, 0, stream>>>(qkv_w, wqkv, 786432);
    f32_to_bf16_k<<<262144 / 256, 256, 0, stream>>>(proj_w, wproj, 262144);
    mask_reduce_k<<<2 * 32 * 32, 256, 0, stream>>>(mask, mflag);
    gemm_qkv8_k<<<192, 512, 0, stream>>>(xb, wqkv, qkv_b, qg, kg, vtg);
    attn_k<<<512, 256, 0, stream>>>(qg, kg, vtg, mflag, mask, ao);
    gemm_bt_k<0><<<32 * 8, 256, 0, stream>>>(ao, wproj, proj_b, 4096, 1024, 1024,
                                             out);
}